// Round 15
// baseline (89.214 us; speedup 1.0000x reference)
//
#include <hip/hip_runtime.h>
#include <hip/hip_bf16.h>

// 3D db4 DWT, fused single kernel.
// Round-13: DMA insts 112 -> 21/wave using ONLY HW-verified widths:
// group = 8 rows x 72 floats = 576 floats = 2 x width-16 + 1 x width-4.
// Stage window cbase=2*wo0-4 (16B-aligned sources); taps at odd float
// offsets -> 5 float2 reads/row, a_j = f[2wo+1+j]. Edge blocks: clamped
// chunks + register tap fixups. vmcnt(3)/(0) gating. Vbuf sh-split
// (16KB LDS + 8 VGPR) keeps LDS at 52KB -> 3 blocks/CU.
// x: [4,3,32,256,256] f32 -> out: [4,24,16,128,128] f32
// out[b, (4*st+2*sh+sw)*3+c, to, ho, wo]

#define CC 3
#define TT 32
#define HH 256
#define WW 256
#define TOH 16
#define HOH 128
#define WOH 128
#define TH 4
#define TW 32
#define NROWS 14
#define NTHREADS 512

constexpr float GLO[8] = {
     0.23037781330885523f,  0.7148465705525415f,   0.6308807679295904f,
    -0.02798376941698385f, -0.18703481171888114f,  0.030841381835986965f,
     0.032883011666982945f, -0.010597401784997278f };
constexpr float GHI[8] = {
    -0.010597401784997278f, -0.032883011666982945f, 0.030841381835986965f,
     0.18703481171888114f,  -0.02798376941698385f,  -0.6308807679295904f,
     0.7148465705525415f,   -0.23037781330885523f };

__device__ __forceinline__ int refl(int p, int n) {
    p = p < 0 ? -p : p;
    p = p >= n ? 2 * n - 2 - p : p;
    return p;
}

__device__ __forceinline__ unsigned short f2bfbits(float f) {
    __hip_bfloat16 h = __float2bfloat16(f);
    return reinterpret_cast<unsigned short&>(h);
}
__device__ __forceinline__ __hip_bfloat16 bits2bf(unsigned short u) {
    __hip_bfloat16 h;
    reinterpret_cast<unsigned short&>(h) = u;
    return h;
}

__global__ __launch_bounds__(NTHREADS, 6)
void dwt3d_db4_kernel(const float* __restrict__ x, float* __restrict__ out) {
    // Ring: 8 waves x 2 slots x (8 rows x 72 floats) = 36864B
    __shared__ float Ring[8 * 1152];
    // Vbuf2: [32 t][256 cols] bf16 (one sh-half at a time) = 16384B
    __shared__ __hip_bfloat16 Vbuf2[TT * 256];

    const int tid  = threadIdx.x;
    const int wid  = tid >> 6;
    const int lane = tid & 63;
    const int wo   = lane & 31;
    const int p    = lane >> 5;          // row parity; also = sw

    // XCD-aware bijective swizzle (1536 blocks, 8 XCDs)
    const int lin = blockIdx.x;
    const int nid = (lin & 7) * 192 + (lin >> 3);
    const int wo0 = (nid & 3) * TW;
    const int ho0 = ((nid >> 2) & 31) * TH;
    const int bz  = nid >> 7;
    const int b = bz / CC, c = bz - b * CC;

    const float* xs = x + (size_t)bz * (TT * HH * WW);
    const int t0 = wid * 4;

    // ---- per-lane DMA geometry (t-invariant) ----
    // Row layout in LDS: 72 floats, float f <-> global col cbase+f.
    const int cbase = 2 * wo0 - 4;       // multiple of 4 -> 16B-aligned srcs
    int lrow[2], scol[2], scol2;
    {
#pragma unroll
        for (int q = 0; q < 2; ++q) {
            const int u = 64 * q + lane;
            const int lr = u / 18;
            const int lc = u - 18 * lr;
            lrow[q] = lr;
            int sc = cbase + 4 * lc;
            if (wo0 == 0  && lc == 0)  sc = 0;    // clamp (floats never read)
            if (wo0 == 96 && lc == 17) sc = 252;  // clamp (floats never read)
            scol[q] = sc;
        }
        // q=2: width-4, row 7, f_in_row = 8+lane
        int sc = cbase + 8 + lane;
        if (wo0 == 96 && lane >= 60) sc = 192 + lane;  // cols 252..255 (dup)
        scol2 = sc;
    }
    float* const ringw = &Ring[wid * 1152];

#define ISSUE_GROUP(g_) do {                                                  \
        _Pragma("unroll")                                                     \
        for (int q_ = 0; q_ < 2; ++q_) {                                      \
            const int rr_ = 8 * (g_) + lrow[q_];                              \
            const int tq_ = rr_ / NROWS, rq_ = rr_ - NROWS * tq_;             \
            const int grow_ = refl(2 * ho0 - 3 + rq_, HH);                    \
            const float* src_ = xs + (size_t)(t0 + tq_) * (HH * WW)           \
                                + grow_ * WW + scol[q_];                      \
            __builtin_amdgcn_global_load_lds(                                 \
                (const __attribute__((address_space(1))) void*)src_,          \
                (__attribute__((address_space(3))) void*)                     \
                    (ringw + ((g_) & 1) * 576 + q_ * 256), 16, 0, 0);         \
        }                                                                     \
        {                                                                     \
            const int rr_ = 8 * (g_) + 7;                                     \
            const int tq_ = rr_ / NROWS, rq_ = rr_ - NROWS * tq_;             \
            const int grow_ = refl(2 * ho0 - 3 + rq_, HH);                    \
            const float* src_ = xs + (size_t)(t0 + tq_) * (HH * WW)           \
                                + grow_ * WW + scol2;                         \
            __builtin_amdgcn_global_load_lds(                                 \
                (const __attribute__((address_space(1))) void*)src_,          \
                (__attribute__((address_space(3))) void*)                     \
                    (ringw + ((g_) & 1) * 576 + 512), 4, 0, 0);               \
        }                                                                     \
    } while (0)

    // Hoisted parity-selected H weights
    float wH0[4], wH1[4];
#pragma unroll
    for (int d = 0; d < 4; ++d) {
        wH0[d] = p ? GLO[2 * d + 1] : GLO[2 * d];
        wH1[d] = p ? GHI[2 * d + 1] : GHI[2 * d];
    }

    const float2* Ring2 = (const float2*)Ring;
    const int r2base = wid * 576 + wo;   // float2 units; row offset added per k

    float vacc0[2][4], vacc1[2][4];
#pragma unroll
    for (int sh = 0; sh < 2; ++sh)
#pragma unroll
        for (int ho = 0; ho < 4; ++ho) { vacc0[sh][ho] = 0.f; vacc1[sh][ho] = 0.f; }

    unsigned pkA[4], pkB[4];   // held sh=1 results, packed bf16

    ISSUE_GROUP(0);
    ISSUE_GROUP(1);

#pragma unroll
    for (int k = 0; k < 28; ++k) {
        if (k < 24) asm volatile("s_waitcnt vmcnt(3)" ::: "memory");
        else        asm volatile("s_waitcnt vmcnt(0)" ::: "memory");

        // lane's row = 2k+p; taps at floats 2wo+1..2wo+8 -> 5 float2 reads
        const int soff = ((k >> 2) & 1) * 288 + (k & 3) * 72 + p * 36;
        const float2 d0 = Ring2[r2base + soff + 0];
        const float2 d1 = Ring2[r2base + soff + 1];
        const float2 d2 = Ring2[r2base + soff + 2];
        const float2 d3 = Ring2[r2base + soff + 3];
        const float2 d4 = Ring2[r2base + soff + 4];

        float a0 = d0.y, a1 = d1.x, a2 = d1.y, a3 = d2.x;
        float a4 = d2.y, a5 = d3.x, a6 = d3.y, a7 = d4.x;

        // reflect fixups (block-uniform outer branches, register-only)
        if (wo0 == 0) {
            if (wo == 0)      { a0 = d3.y; a1 = d3.x; a2 = d2.y; }
            else if (wo == 1) { a0 = d1.y; }
        } else if (wo0 == 96) {
            if (wo == 30)      { a7 = d3.x; }
            else if (wo == 31) { a5 = d2.x; a6 = d1.y; a7 = d1.x; }
        }

        float m_lo, m_hi;
        m_lo = a0 * GLO[0]; m_hi = a0 * GHI[0];
        m_lo = fmaf(a1, GLO[1], m_lo); m_hi = fmaf(a1, GHI[1], m_hi);
        m_lo = fmaf(a2, GLO[2], m_lo); m_hi = fmaf(a2, GHI[2], m_hi);
        m_lo = fmaf(a3, GLO[3], m_lo); m_hi = fmaf(a3, GHI[3], m_hi);
        m_lo = fmaf(a4, GLO[4], m_lo); m_hi = fmaf(a4, GHI[4], m_hi);
        m_lo = fmaf(a5, GLO[5], m_lo); m_hi = fmaf(a5, GHI[5], m_hi);
        m_lo = fmaf(a6, GLO[6], m_lo); m_hi = fmaf(a6, GHI[6], m_hi);
        m_lo = fmaf(a7, GLO[7], m_lo); m_hi = fmaf(a7, GHI[7], m_hi);

        // refill: issue group g+2 after group g's taps were consumed
        if (((k & 3) == 3) && k <= 19) {
            __builtin_amdgcn_sched_barrier(0);
            ISSUE_GROUP((k >> 2) + 2);
        }

        const int kk = k % 7;
#pragma unroll
        for (int ho = 0; ho < 4; ++ho) {
            const int d = kk - ho;
            if (d >= 0 && d < 4) {
                vacc0[0][ho] = fmaf(m_lo, wH0[d], vacc0[0][ho]);
                vacc0[1][ho] = fmaf(m_lo, wH1[d], vacc0[1][ho]);
                vacc1[0][ho] = fmaf(m_hi, wH0[d], vacc1[0][ho]);
                vacc1[1][ho] = fmaf(m_hi, wH1[d], vacc1[1][ho]);
            }
        }

        if (kk == 6) {   // slice boundary
            const int t  = t0 + k / 7;
            const int si = k / 7;
            unsigned w0 = 0, w1 = 0;
#pragma unroll
            for (int ho = 0; ho < 4; ++ho) {
                {
                    const float send = p ? vacc0[0][ho] : vacc1[0][ho];
                    const float keep = p ? vacc1[0][ho] : vacc0[0][ho];
                    const float recv = __shfl_xor(send, 32, 64);
                    Vbuf2[t * 256 + p * 128 + ho * 32 + wo] =
                        __float2bfloat16(keep + recv);
                }
                {
                    const float send = p ? vacc0[1][ho] : vacc1[1][ho];
                    const float keep = p ? vacc1[1][ho] : vacc0[1][ho];
                    const float recv = __shfl_xor(send, 32, 64);
                    const unsigned us = f2bfbits(keep + recv);
                    if (ho == 0) w0 = us;
                    if (ho == 1) w0 |= us << 16;
                    if (ho == 2) w1 = us;
                    if (ho == 3) w1 |= us << 16;
                }
                vacc0[0][ho] = 0.f; vacc0[1][ho] = 0.f;
                vacc1[0][ho] = 0.f; vacc1[1][ho] = 0.f;
            }
            pkA[si] = w0; pkB[si] = w1;
        }
    }

    __syncthreads();

    // ---- T transform, pass A (sh=0); refill Vbuf2 with sh=1; pass B.
    const int colA = tid & 255;
    const int tohalf = tid >> 8;            // wave-uniform
    const int swT = colA >> 7, hoT = (colA >> 5) & 3, woT = colA & 31;
    const size_t hwoff = (size_t)(ho0 + hoT) * WOH + (wo0 + woT);

    float v[22];
    if (tid < 256) {
#pragma unroll
        for (int i = 0; i < 22; ++i)
            v[i] = __bfloat162float(Vbuf2[refl(i - 3, TT) * 256 + colA]);
    } else {
#pragma unroll
        for (int i = 0; i < 22; ++i)
            v[i] = __bfloat162float(Vbuf2[refl(13 + i, TT) * 256 + colA]);
    }
    __syncthreads();

#pragma unroll
    for (int si = 0; si < 4; ++si) {
        const int t = t0 + si;
        const unsigned w0 = pkA[si], w1 = pkB[si];
        Vbuf2[t * 256 + p * 128 + 0 * 32 + wo] = bits2bf((unsigned short)(w0 & 0xffff));
        Vbuf2[t * 256 + p * 128 + 1 * 32 + wo] = bits2bf((unsigned short)(w0 >> 16));
        Vbuf2[t * 256 + p * 128 + 2 * 32 + wo] = bits2bf((unsigned short)(w1 & 0xffff));
        Vbuf2[t * 256 + p * 128 + 3 * 32 + wo] = bits2bf((unsigned short)(w1 >> 16));
    }
    __syncthreads();

#define TCOMPUTE(sh_) do {                                                    \
        const int ch_lo = (0 + 2 * (sh_) + swT) * CC + c;                     \
        const int ch_hi = (4 + 2 * (sh_) + swT) * CC + c;                     \
        _Pragma("unroll")                                                     \
        for (int tl = 0; tl < 8; ++tl) {                                      \
            float lo = 0.f, hi = 0.f;                                         \
            _Pragma("unroll")                                                 \
            for (int j = 0; j < 8; ++j) {                                     \
                const float vv = v[2 * tl + j];                               \
                lo = fmaf(vv, GLO[j], lo);                                    \
                hi = fmaf(vv, GHI[j], hi);                                    \
            }                                                                 \
            const int to = tohalf * 8 + tl;                                   \
            out[((size_t)(b * 24 + ch_lo) * TOH + to) * (HOH * WOH) + hwoff] = lo; \
            out[((size_t)(b * 24 + ch_hi) * TOH + to) * (HOH * WOH) + hwoff] = hi; \
        }                                                                     \
    } while (0)

    TCOMPUTE(0);

    if (tid < 256) {
#pragma unroll
        for (int i = 0; i < 22; ++i)
            v[i] = __bfloat162float(Vbuf2[refl(i - 3, TT) * 256 + colA]);
    } else {
#pragma unroll
        for (int i = 0; i < 22; ++i)
            v[i] = __bfloat162float(Vbuf2[refl(13 + i, TT) * 256 + colA]);
    }
    TCOMPUTE(1);
}

extern "C" void kernel_launch(void* const* d_in, const int* in_sizes, int n_in,
                              void* d_out, int out_size, void* d_ws, size_t ws_size,
                              hipStream_t stream) {
    (void)in_sizes; (void)n_in; (void)d_ws; (void)ws_size; (void)out_size;
    const float* x = (const float*)d_in[0];
    float* out = (float*)d_out;
    dim3 grid(1536, 1, 1);
    dim3 block(NTHREADS);
    hipLaunchKernelGGL(dwt3d_db4_kernel, grid, block, 0, stream, x, out);
}

// Round 16
// 49.595 us; speedup vs baseline: 1.7988x; 1.7988x over previous
//
#include <hip/hip_runtime.h>
#include <hip/hip_bf16.h>

// 3D db4 DWT, fused single kernel.
// Round-16: r11 structure (proven 43.9us epilogue) + DMA insts 112 -> 28/wave:
// ONE width-16 global_load_lds per 2-row pair (64 lanes x 16B = 256 floats =
// pair(144) + 112-float spill into next slot with IDENTICAL values — benign
// dup, r11-proven pattern). Ring = 3 pair-slots(144) + 112 tail pad = 544
// floats/wave; LDS 49KB -> 3 blocks/CU. Gates vmcnt(1)/(0).
// (r15 lesson: r13's sh-split/pk epilogue forced scratch spills — 220MB HBM
// writes; reverted to r11 epilogue, no small arrays with runtime indices.)
// x: [4,3,32,256,256] f32 -> out: [4,24,16,128,128] f32
// out[b, (4*st+2*sh+sw)*3+c, to, ho, wo]

#define CC 3
#define TT 32
#define HH 256
#define WW 256
#define TOH 16
#define HOH 128
#define WOH 128
#define TH 4
#define TW 32
#define NROWS 14
#define NTHREADS 512
#define VSTR 512        // Vbuf row stride (bf16)
#define RWAVE 544       // ring floats per wave: 3*144 + 112 pad

constexpr float GLO[8] = {
     0.23037781330885523f,  0.7148465705525415f,   0.6308807679295904f,
    -0.02798376941698385f, -0.18703481171888114f,  0.030841381835986965f,
     0.032883011666982945f, -0.010597401784997278f };
constexpr float GHI[8] = {
    -0.010597401784997278f, -0.032883011666982945f, 0.030841381835986965f,
     0.18703481171888114f,  -0.02798376941698385f,  -0.6308807679295904f,
     0.7148465705525415f,   -0.23037781330885523f };

__device__ __forceinline__ int refl(int p, int n) {
    p = p < 0 ? -p : p;
    p = p >= n ? 2 * n - 2 - p : p;
    return p;
}

__global__ __launch_bounds__(NTHREADS)
void dwt3d_db4_kernel(const float* __restrict__ x, float* __restrict__ out) {
    __shared__ float Ring[8 * RWAVE];             // 17408 B
    __shared__ __hip_bfloat16 Vbuf[TT * VSTR];    // 32768 B

    const int tid  = threadIdx.x;
    const int wid  = tid >> 6;
    const int lane = tid & 63;
    const int wo   = lane & 31;          // lane's output-w column
    const int p    = lane >> 5;          // row parity (0=even,1=odd)

    // XCD-aware bijective swizzle: 1536 blocks, 8 XCDs, 192 per chunk.
    const int lin = blockIdx.x;
    const int nid = (lin & 7) * 192 + (lin >> 3);
    const int wo0 = (nid & 3) * TW;
    const int ho0 = ((nid >> 2) & 31) * TH;
    const int bz  = nid >> 7;            // b*CC + c
    const int b = bz / CC, c = bz - b * CC;

    const float* xs = x + (size_t)bz * (TT * HH * WW);
    const int t0 = wid * 4;              // this wave's 4 slices

    // ---- per-lane DMA geometry (t-invariant) ----
    // Pair layout: 144 floats = row(2k) f0..71 | row(2k+1) f72..143; float f
    // of a row holds global col cbase+f. One width-16 inst: lane writes
    // floats 4*lane..4*lane+3 -> lane u: rowoff=u/18 (0..3; 2,3 = spill into
    // next pair as identical dup), col=cbase+4*(u%18).
    const int cbase = 2 * wo0 - 4;       // multiple of 4 -> 16B-aligned srcs
    const int rowoff = lane / 18;        // 0..3 (lane-const)
    const int lcq = lane - 18 * rowoff;  // 0..17
    int scol = cbase + 4 * lcq;
    if (wo0 == 0  && lcq == 0)  scol = 0;    // left clamp (fixups cover)
    if (wo0 == 96 && lcq == 17) scol = 252;  // right clamp (fixups cover)

    float* const ringw = &Ring[wid * RWAVE];

#define ISSUE(k_) do {                                                        \
        int rr_ = 2 * (k_) + rowoff;                                          \
        rr_ = rr_ > 55 ? 55 : rr_;       /* clamp: spill of last pair */      \
        const int tq_ = (rr_ * 2341) >> 15;          /* rr/14, rr<=58 */      \
        const int rq_ = rr_ - 14 * tq_;                                       \
        const int grow_ = refl(2 * ho0 - 3 + rq_, HH);                        \
        const float* src_ = xs + (size_t)(t0 + tq_) * (HH * WW)               \
                            + grow_ * WW + scol;                              \
        __builtin_amdgcn_global_load_lds(                                     \
            (const __attribute__((address_space(1))) void*)src_,              \
            (__attribute__((address_space(3))) void*)                         \
                (ringw + ((k_) % 3) * 144), 16, 0, 0);                        \
    } while (0)

    // Hoisted parity-selected H weights: row r=2k'+p -> weight G[2d+p].
    float wH0[4], wH1[4];
#pragma unroll
    for (int d = 0; d < 4; ++d) {
        wH0[d] = p ? GLO[2 * d + 1] : GLO[2 * d];
        wH1[d] = p ? GHI[2 * d + 1] : GHI[2 * d];
    }

    const float2* Ring2 = (const float2*)Ring;
    const int r2base = wid * (RWAVE / 2) + p * 36 + wo;  // float2 units
    const int vcolbase = p * 128 + wo;                   // Vbuf col base

    float vacc0[2][4], vacc1[2][4];
#pragma unroll
    for (int sh = 0; sh < 2; ++sh)
#pragma unroll
        for (int ho = 0; ho < 4; ++ho) { vacc0[sh][ho] = 0.f; vacc1[sh][ho] = 0.f; }

    ISSUE(0);
    ISSUE(1);

#pragma unroll
    for (int k = 0; k < 28; ++k) {
        // 1 inst/pair: issued = k+2 before wait; pair k resident <=> inst k
        // retired -> vmcnt(1) steady; k=27: all must retire.
        if (k <= 26) asm volatile("s_waitcnt vmcnt(1)" ::: "memory");
        else         asm volatile("s_waitcnt vmcnt(0)" ::: "memory");

        // lane's row = 2k+p; taps at floats 2wo+1..2wo+8 -> 5 float2 reads
        const int soff = (k % 3) * 72;   // compile-time under unroll
        const float2 d0 = Ring2[r2base + soff + 0];
        const float2 d1 = Ring2[r2base + soff + 1];
        const float2 d2 = Ring2[r2base + soff + 2];
        const float2 d3 = Ring2[r2base + soff + 3];
        const float2 d4 = Ring2[r2base + soff + 4];

        float a0 = d0.y, a1 = d1.x, a2 = d1.y, a3 = d2.x;
        float a4 = d2.y, a5 = d3.x, a6 = d3.y, a7 = d4.x;

        // reflect fixups (block-uniform outer branches, register-only)
        if (wo0 == 0) {
            if (wo == 0)      { a0 = d3.y; a1 = d3.x; a2 = d2.y; }
            else if (wo == 1) { a0 = d1.y; }
        } else if (wo0 == 96) {
            if (wo == 30)      { a7 = d3.x; }
            else if (wo == 31) { a5 = d2.x; a6 = d1.y; a7 = d1.x; }
        }

        float m_lo, m_hi;
        m_lo = a0 * GLO[0]; m_hi = a0 * GHI[0];
        m_lo = fmaf(a1, GLO[1], m_lo); m_hi = fmaf(a1, GHI[1], m_hi);
        m_lo = fmaf(a2, GLO[2], m_lo); m_hi = fmaf(a2, GHI[2], m_hi);
        m_lo = fmaf(a3, GLO[3], m_lo); m_hi = fmaf(a3, GHI[3], m_hi);
        m_lo = fmaf(a4, GLO[4], m_lo); m_hi = fmaf(a4, GHI[4], m_hi);
        m_lo = fmaf(a5, GLO[5], m_lo); m_hi = fmaf(a5, GHI[5], m_hi);
        m_lo = fmaf(a6, GLO[6], m_lo); m_hi = fmaf(a6, GHI[6], m_hi);
        m_lo = fmaf(a7, GLO[7], m_lo); m_hi = fmaf(a7, GHI[7], m_hi);

        // refill: slot (k+2)%3 = slot of pair k-1, consumed at iter k-1
        if (k <= 25) ISSUE(k + 2);

        // H accumulation (parity-local), kk = slice-local row-pair index
        const int kk = k % 7;
#pragma unroll
        for (int ho = 0; ho < 4; ++ho) {
            const int d = kk - ho;
            if (d >= 0 && d < 4) {
                vacc0[0][ho] = fmaf(m_lo, wH0[d], vacc0[0][ho]);
                vacc0[1][ho] = fmaf(m_lo, wH1[d], vacc0[1][ho]);
                vacc1[0][ho] = fmaf(m_hi, wH0[d], vacc1[0][ho]);
                vacc1[1][ho] = fmaf(m_hi, wH1[d], vacc1[1][ho]);
            }
        }

        // slice boundary: merge parity partials across lane pairs -> Vbuf
        if (kk == 6) {
            const int t = t0 + k / 7;
#pragma unroll
            for (int sh = 0; sh < 2; ++sh)
#pragma unroll
                for (int ho = 0; ho < 4; ++ho) {
                    const float send = p ? vacc0[sh][ho] : vacc1[sh][ho];
                    const float keep = p ? vacc1[sh][ho] : vacc0[sh][ho];
                    const float recv = __shfl_xor(send, 32, 64);
                    Vbuf[t * VSTR + sh * 256 + vcolbase + ho * 32] =
                        __float2bfloat16(keep + recv);
                    vacc0[sh][ho] = 0.f; vacc1[sh][ho] = 0.f;
                }
        }
    }

    __syncthreads();

    // ---- T transform (registers) + store (r11 verbatim) ----
    float v[TT];
#pragma unroll
    for (int t = 0; t < TT; ++t) v[t] = __bfloat162float(Vbuf[t * VSTR + tid]);

    const int subhw = tid >> 7;
    const int hoq   = (tid >> 5) & 3;
    const int wo2   = tid & 31;

    const size_t hw = (size_t)(ho0 + hoq) * WOH + (wo0 + wo2);
    const size_t ch_lo = (size_t)(subhw * CC + c);
    const size_t ch_hi = (size_t)((4 + subhw) * CC + c);
    const size_t o_lo = (((size_t)b * 24 + ch_lo) * TOH) * (HOH * WOH) + hw;
    const size_t o_hi = (((size_t)b * 24 + ch_hi) * TOH) * (HOH * WOH) + hw;

#pragma unroll
    for (int to = 0; to < TOH; ++to) {
        float lo = 0.f, hi = 0.f;
#pragma unroll
        for (int j = 0; j < 8; ++j) {
            int q = 2 * to + j - 3;
            q = q < 0 ? -q : q;
            q = q >= TT ? 2 * TT - 2 - q : q;   // folds to constant
            lo = fmaf(v[q], GLO[j], lo);
            hi = fmaf(v[q], GHI[j], hi);
        }
        out[o_lo + (size_t)to * (HOH * WOH)] = lo;
        out[o_hi + (size_t)to * (HOH * WOH)] = hi;
    }
}

extern "C" void kernel_launch(void* const* d_in, const int* in_sizes, int n_in,
                              void* d_out, int out_size, void* d_ws, size_t ws_size,
                              hipStream_t stream) {
    (void)in_sizes; (void)n_in; (void)d_ws; (void)ws_size; (void)out_size;
    const float* x = (const float*)d_in[0];
    float* out = (float*)d_out;
    dim3 grid(1536, 1, 1);               // flattened; swizzle decodes (x,y,z)
    dim3 block(NTHREADS);
    hipLaunchKernelGGL(dwt3d_db4_kernel, grid, block, 0, stream, x, out);
}

// Round 18
// 45.569 us; speedup vs baseline: 1.9578x; 1.0884x over previous
//
#include <hip/hip_runtime.h>
#include <hip/hip_bf16.h>

// 3D db4 DWT, fused single kernel.
// Round-18 = Round-17 with the staging regression fixed: chunk-1 restored to
// r11's overlap scheme (cols 3..66 -> dest lp_+6; overlap floats 6..63 carry
// IDENTICAL values, zero spill past float 69 < RSLOT=72). r17 had accidentally
// used r8's dup-lane chunk-1 (dest lp_+64) which spills into the next slot at
// RSLOT=72 — the r10 race.
// One-generation grid: 768 blocks (3/CU x 256 CU); each block runs TWO bz
// channels back-to-back; half-1's first 6 rows prefetched during half-0's
// T-phase. x: [4,3,32,256,256] f32 -> out: [4,24,16,128,128] f32

#define CC 3
#define TT 32
#define HH 256
#define WW 256
#define TOH 16
#define HOH 128
#define WOH 128
#define TH 4
#define TW 32
#define NROWS 14
#define RSLOT 72        // ring slot stride (floats)
#define RSLOT2 36
#define NSLOTS 8
#define DEPTH 6
#define NTHREADS 512
#define VSTR 512
#define NRR (4*NROWS)   // 56 rows per wave per half

constexpr float GLO[8] = {
     0.23037781330885523f,  0.7148465705525415f,   0.6308807679295904f,
    -0.02798376941698385f, -0.18703481171888114f,  0.030841381835986965f,
     0.032883011666982945f, -0.010597401784997278f };
constexpr float GHI[8] = {
    -0.010597401784997278f, -0.032883011666982945f, 0.030841381835986965f,
     0.18703481171888114f,  -0.02798376941698385f,  -0.6308807679295904f,
     0.7148465705525415f,   -0.23037781330885523f };

__device__ __forceinline__ int refl(int p, int n) {
    p = p < 0 ? -p : p;
    p = p >= n ? 2 * n - 2 - p : p;
    return p;
}

__global__ __launch_bounds__(NTHREADS)
void dwt3d_db4_kernel(const float* __restrict__ x, float* __restrict__ out) {
    __shared__ float Ring[8 * NSLOTS * RSLOT];    // 18432 B
    __shared__ __hip_bfloat16 Vbuf[TT * VSTR];    // 32768 B

    const int tid  = threadIdx.x;
    const int wid  = tid >> 6;
    const int lane = tid & 63;
    const int wo   = lane & 31;
    const int p    = lane >> 5;          // row parity (0=even,1=odd)

    // XCD-aware bijective swizzle: 768 blocks, 8 XCDs, 96 per chunk.
    const int lin = blockIdx.x;
    const int nid = (lin & 7) * 96 + (lin >> 3);
    const int wo0 = (nid & 3) * TW;
    const int ho0 = ((nid >> 2) & 31) * TH;
    const int g   = nid >> 7;            // 0..5 -> bz pair (2g, 2g+1)

    const int t0 = wid * 4;
    const float* const xs0 = x + (size_t)(2 * g)     * (TT * HH * WW);
    const float* const xs1 = x + (size_t)(2 * g + 1) * (TT * HH * WW);

    // r11 overlap staging: chunk-0 cols -3..60 -> floats 0..63 (dest lp_);
    // chunk-1 cols 3..66 -> floats 6..69 (dest lp_+6). Overlap floats 6..63
    // written with IDENTICAL values by both chunks -> benign race, no spill.
    const int gcol0 = refl(2 * wo0 - 3 + lane, WW);
    const int gcol1 = refl(2 * wo0 + 3 + lane, WW);

    // parity-selected H weights
    float wH0[4], wH1[4];
#pragma unroll
    for (int d = 0; d < 4; ++d) {
        wH0[d] = p ? GLO[2 * d + 1] : GLO[2 * d];
        wH1[d] = p ? GHI[2 * d + 1] : GHI[2 * d];
    }

    const int ringbase = wid * (NSLOTS * RSLOT);
    const float2* Ring2 = (const float2*)Ring;
    const int r2base = wid * (NSLOTS * RSLOT2) + p * RSLOT2 + wo;
    const int vcolbase = p * 128 + wo;

#define ISSUE(xs_, rr_) do {                                                  \
        const int t_ = (rr_) / NROWS, r_ = (rr_) % NROWS;                     \
        const int gr_ = refl(2 * ho0 - 3 + r_, HH);                           \
        const float* rowp_ = (xs_) + (size_t)(t0 + t_) * (HH * WW) + gr_ * WW;\
        float* lp_ = &Ring[ringbase + ((rr_) & (NSLOTS - 1)) * RSLOT];        \
        __builtin_amdgcn_global_load_lds(                                     \
            (const __attribute__((address_space(1))) void*)(rowp_ + gcol0),   \
            (__attribute__((address_space(3))) void*)lp_, 4, 0, 0);           \
        __builtin_amdgcn_global_load_lds(                                     \
            (const __attribute__((address_space(1))) void*)(rowp_ + gcol1),   \
            (__attribute__((address_space(3))) void*)(lp_ + 6), 4, 0, 0);     \
    } while (0)

    float vacc0[2][4], vacc1[2][4];
#pragma unroll
    for (int sh = 0; sh < 2; ++sh)
#pragma unroll
        for (int ho = 0; ho < 4; ++ho) { vacc0[sh][ho] = 0.f; vacc1[sh][ho] = 0.f; }

// Main W+H loop over one bz's 28 row-pairs (r11 verbatim; gates 8/4/0).
#define MAINLOOP(xs_) do {                                                    \
    _Pragma("unroll")                                                         \
    for (int k = 0; k < 28; ++k) {                                            \
        if (k <= 25)      asm volatile("s_waitcnt vmcnt(8)" ::: "memory");    \
        else if (k == 26) asm volatile("s_waitcnt vmcnt(4)" ::: "memory");    \
        else              asm volatile("s_waitcnt vmcnt(0)" ::: "memory");    \
        const int soff = ((2 * k) & (NSLOTS - 1)) * RSLOT2;                   \
        const float2 d0 = Ring2[r2base + soff + 0];                           \
        const float2 d1 = Ring2[r2base + soff + 1];                           \
        const float2 d2 = Ring2[r2base + soff + 2];                           \
        const float2 d3 = Ring2[r2base + soff + 3];                           \
        float a0 = d0.x, a1 = d0.y, a2 = d1.x, a3 = d1.y;                     \
        float a4 = d2.x, a5 = d2.y, a6 = d3.x, a7 = d3.y;                     \
        float m_lo, m_hi;                                                     \
        m_lo = a0 * GLO[0]; m_hi = a0 * GHI[0];                               \
        m_lo = fmaf(a1, GLO[1], m_lo); m_hi = fmaf(a1, GHI[1], m_hi);         \
        m_lo = fmaf(a2, GLO[2], m_lo); m_hi = fmaf(a2, GHI[2], m_hi);         \
        m_lo = fmaf(a3, GLO[3], m_lo); m_hi = fmaf(a3, GHI[3], m_hi);         \
        m_lo = fmaf(a4, GLO[4], m_lo); m_hi = fmaf(a4, GHI[4], m_hi);         \
        m_lo = fmaf(a5, GLO[5], m_lo); m_hi = fmaf(a5, GHI[5], m_hi);         \
        m_lo = fmaf(a6, GLO[6], m_lo); m_hi = fmaf(a6, GHI[6], m_hi);         \
        m_lo = fmaf(a7, GLO[7], m_lo); m_hi = fmaf(a7, GHI[7], m_hi);         \
        if (2 * k + 6 < NRR) { ISSUE(xs_, 2 * k + 6); ISSUE(xs_, 2 * k + 7); }\
        const int kk = k % 7;                                                 \
        _Pragma("unroll")                                                     \
        for (int ho = 0; ho < 4; ++ho) {                                      \
            const int d = kk - ho;                                            \
            if (d >= 0 && d < 4) {                                            \
                vacc0[0][ho] = fmaf(m_lo, wH0[d], vacc0[0][ho]);              \
                vacc0[1][ho] = fmaf(m_lo, wH1[d], vacc0[1][ho]);              \
                vacc1[0][ho] = fmaf(m_hi, wH0[d], vacc1[0][ho]);              \
                vacc1[1][ho] = fmaf(m_hi, wH1[d], vacc1[1][ho]);              \
            }                                                                 \
        }                                                                     \
        if (kk == 6) {                                                        \
            const int t = t0 + k / 7;                                         \
            _Pragma("unroll")                                                 \
            for (int sh = 0; sh < 2; ++sh)                                    \
                _Pragma("unroll")                                             \
                for (int ho = 0; ho < 4; ++ho) {                              \
                    const float send = p ? vacc0[sh][ho] : vacc1[sh][ho];     \
                    const float keep = p ? vacc1[sh][ho] : vacc0[sh][ho];     \
                    const float recv = __shfl_xor(send, 32, 64);              \
                    Vbuf[t * VSTR + sh * 256 + vcolbase + ho * 32] =          \
                        __float2bfloat16(keep + recv);                        \
                    vacc0[sh][ho] = 0.f; vacc1[sh][ho] = 0.f;                 \
                }                                                             \
        }                                                                     \
    }                                                                         \
} while (0)

// T transform + store for channel bz_ (r11 verbatim, bz-parameterized)
#define TPHASE(bz_) do {                                                      \
    float v[TT];                                                              \
    _Pragma("unroll")                                                         \
    for (int t = 0; t < TT; ++t)                                              \
        v[t] = __bfloat162float(Vbuf[t * VSTR + tid]);                        \
    const int b_ = (bz_) / CC, c_ = (bz_) - b_ * CC;                          \
    const int subhw = tid >> 7;                                               \
    const int hoq   = (tid >> 5) & 3;                                         \
    const int wo2   = tid & 31;                                               \
    const size_t hw = (size_t)(ho0 + hoq) * WOH + (wo0 + wo2);                \
    const size_t ch_lo = (size_t)(subhw * CC + c_);                           \
    const size_t ch_hi = (size_t)((4 + subhw) * CC + c_);                     \
    const size_t o_lo = (((size_t)b_ * 24 + ch_lo) * TOH) * (HOH * WOH) + hw; \
    const size_t o_hi = (((size_t)b_ * 24 + ch_hi) * TOH) * (HOH * WOH) + hw; \
    _Pragma("unroll")                                                         \
    for (int to = 0; to < TOH; ++to) {                                        \
        float lo = 0.f, hi = 0.f;                                             \
        _Pragma("unroll")                                                     \
        for (int j = 0; j < 8; ++j) {                                         \
            int q = 2 * to + j - 3;                                           \
            q = q < 0 ? -q : q;                                               \
            q = q >= TT ? 2 * TT - 2 - q : q;                                 \
            lo = fmaf(v[q], GLO[j], lo);                                      \
            hi = fmaf(v[q], GHI[j], hi);                                      \
        }                                                                     \
        out[o_lo + (size_t)to * (HOH * WOH)] = lo;                            \
        out[o_hi + (size_t)to * (HOH * WOH)] = hi;                            \
    }                                                                         \
} while (0)

    // ---- half 0 ----
#pragma unroll
    for (int rr = 0; rr < DEPTH; ++rr) ISSUE(xs0, rr);
    MAINLOOP(xs0);

    // prefetch half-1 rows 0..5 (drain at the next barrier; ring warm for h1)
#pragma unroll
    for (int rr = 0; rr < DEPTH; ++rr) ISSUE(xs1, rr);

    __syncthreads();
    TPHASE(2 * g);
    __syncthreads();           // Vbuf reuse: all T-reads done before h1 writes

    // ---- half 1 (ring pre-filled; gates pass trivially for k<3) ----
    MAINLOOP(xs1);
    __syncthreads();
    TPHASE(2 * g + 1);
}

extern "C" void kernel_launch(void* const* d_in, const int* in_sizes, int n_in,
                              void* d_out, int out_size, void* d_ws, size_t ws_size,
                              hipStream_t stream) {
    (void)in_sizes; (void)n_in; (void)d_ws; (void)ws_size; (void)out_size;
    const float* x = (const float*)d_in[0];
    float* out = (float*)d_out;
    dim3 grid(768, 1, 1);                // one generation: 3 blocks/CU x 256
    dim3 block(NTHREADS);
    hipLaunchKernelGGL(dwt3d_db4_kernel, grid, block, 0, stream, x, out);
}